// Round 1
// baseline (58.585 us; speedup 1.0000x reference)
//
#include <hip/hip_runtime.h>

// label_aware_dual_MSEloss, B=8192, inputs (B,1) fp32 input/target, scalar fp32 out.
//
// Closed form for the pairwise contrastive term (i<j over B samples):
//   e_i = yh_i - y_i
//   num = 0.5 * ( N*S_we2 + S_e2*S_w - 2*S_we*S_e )
//   den = 0.5 * (N-1) * S_w
// where S_w=Σw, S_e=Σe, S_e2=Σe², S_we=Σw·e, S_we2=Σw·e².
// MSE term uses validity-masked sums S_sewv=Σ(y-yh)²·w·valid, S_wv=Σw·valid.

constexpr int BN = 8192;
constexpr int NT = 1024;          // 16 waves, 8 elems/thread
constexpr int NW = NT / 64;

__global__ __launch_bounds__(NT)
void loss_kernel(const float* __restrict__ inp,
                 const float* __restrict__ tgt,
                 float* __restrict__ out) {
    const int tid = threadIdx.x;

    double s_w = 0.0, s_wv = 0.0, s_sewv = 0.0;
    double s_e = 0.0, s_e2 = 0.0, s_we = 0.0, s_we2 = 0.0;

    #pragma unroll
    for (int k = 0; k < BN / NT; ++k) {
        const int i = tid + k * NT;
        const float y  = tgt[i];
        const float yh = inp[i];

        float w = fabsf(0.5f - y) / (0.5f + fabsf(y) + 1e-8f);
        w = fminf(fmaxf(w, 0.1f), 2.0f);

        const bool valid = !(y != y);             // ~isnan(target)
        const float se = valid ? (y - yh) * (y - yh) : 0.0f;
        const float wv = valid ? w : 0.0f;

        const double e  = (double)yh - (double)y;
        const double wd = (double)w;

        s_w    += wd;
        s_wv   += (double)wv;
        s_sewv += (double)se * (double)wv;
        s_e    += e;
        s_e2   += e * e;
        s_we   += wd * e;
        s_we2  += wd * e * e;
    }

    // 64-lane wave reduction (wavefront = 64 on gfx950)
    #pragma unroll
    for (int off = 32; off > 0; off >>= 1) {
        s_w    += __shfl_down(s_w,    off);
        s_wv   += __shfl_down(s_wv,   off);
        s_sewv += __shfl_down(s_sewv, off);
        s_e    += __shfl_down(s_e,    off);
        s_e2   += __shfl_down(s_e2,   off);
        s_we   += __shfl_down(s_we,   off);
        s_we2  += __shfl_down(s_we2,  off);
    }

    __shared__ double red[7][NW];
    const int wave = tid >> 6;
    const int lane = tid & 63;
    if (lane == 0) {
        red[0][wave] = s_w;    red[1][wave] = s_wv;  red[2][wave] = s_sewv;
        red[3][wave] = s_e;    red[4][wave] = s_e2;  red[5][wave] = s_we;
        red[6][wave] = s_we2;
    }
    __syncthreads();

    if (tid == 0) {
        double a[7];
        #pragma unroll
        for (int j = 0; j < 7; ++j) {
            double acc = 0.0;
            #pragma unroll
            for (int m = 0; m < NW; ++m) acc += red[j][m];
            a[j] = acc;
        }
        const double S_w = a[0], S_wv = a[1], S_sewv = a[2];
        const double S_e = a[3], S_e2 = a[4], S_we = a[5], S_we2 = a[6];

        const double mse = S_sewv / S_wv;
        const double N   = (double)BN;
        const double num = 0.5 * (N * S_we2 + S_e2 * S_w - 2.0 * S_we * S_e);
        const double den = 0.5 * (N - 1.0) * S_w;
        const double c   = num / den;

        const bool   do_scale = (c > 1e-8) && (mse > 1e-8) && (c < mse);
        const double scale    = do_scale ? (mse / c) : 1.0;

        out[0] = (float)(0.5 * mse + 0.5 * (c * scale));
    }
}

extern "C" void kernel_launch(void* const* d_in, const int* in_sizes, int n_in,
                              void* d_out, int out_size, void* d_ws, size_t ws_size,
                              hipStream_t stream) {
    const float* inp = (const float*)d_in[0];
    const float* tgt = (const float*)d_in[1];
    float* out = (float*)d_out;
    loss_kernel<<<1, NT, 0, stream>>>(inp, tgt, out);
}

// Round 2
// 56.836 us; speedup vs baseline: 1.0308x; 1.0308x over previous
//
#include <hip/hip_runtime.h>

// label_aware_dual_MSEloss, B=8192, inputs (B,1) fp32, scalar fp32 out.
//
// Closed form for the pairwise contrastive term (i<j over B samples):
//   e_i = yh_i - y_i
//   num = 0.5 * ( N*S_we2 + S_e2*S_w - 2*S_we*S_e )
//   den = 0.5 * (N-1) * S_w
// with moments S_w=Σw, S_e=Σe, S_e2=Σe², S_we=Σw·e, S_we2=Σw·e².
// MSE term uses validity-masked sums S_sewv=Σ valid?w·e²:0, S_wv=Σ valid?w:0.
// (NaN targets: masked sums select 0 before the NaN can propagate, matching
//  jnp.where; the contrastive moments go NaN exactly as the reference does.)
//
// All element math + reductions in fp32 (tree reduction, ~1e-6 rel error vs
// 2e-2 rel threshold); finalize divides in fp64 on thread 0.

constexpr int BN = 8192;
constexpr int NT = 1024;          // 16 waves, 1 block (one reduction, no ws use)
constexpr int NW = NT / 64;
constexpr int NM = 7;             // moments: w, wv, sewv, e, e2, we, we2

__global__ __launch_bounds__(NT)
void loss_kernel(const float4* __restrict__ inp4,
                 const float4* __restrict__ tgt4,
                 float* __restrict__ out) {
    const int tid = threadIdx.x;

    float s[NM];
    #pragma unroll
    for (int j = 0; j < NM; ++j) s[j] = 0.0f;

    // 8192 floats = 2048 float4 per array; 1024 threads -> 2 float4/thread/array
    #pragma unroll
    for (int k = 0; k < BN / (4 * NT); ++k) {
        const float4 y4 = tgt4[tid + k * NT];
        const float4 h4 = inp4[tid + k * NT];
        const float ys[4] = {y4.x, y4.y, y4.z, y4.w};
        const float hs[4] = {h4.x, h4.y, h4.z, h4.w};
        #pragma unroll
        for (int m = 0; m < 4; ++m) {
            const float y  = ys[m];
            const float yh = hs[m];
            float w = fabsf(0.5f - y) / (0.5f + fabsf(y) + 1e-8f);
            w = fminf(fmaxf(w, 0.1f), 2.0f);
            const bool valid = !(y != y);
            const float e  = yh - y;
            const float e2 = e * e;
            s[0] += w;
            s[1] += valid ? w : 0.0f;        // S_wv
            s[2] += valid ? w * e2 : 0.0f;   // S_sewv (se*wv)
            s[3] += e;
            s[4] += e2;
            s[5] += w * e;
            s[6] += w * e2;
        }
    }

    // 64-lane wave tree reduction (fp32)
    #pragma unroll
    for (int off = 32; off > 0; off >>= 1) {
        #pragma unroll
        for (int j = 0; j < NM; ++j) s[j] += __shfl_down(s[j], off);
    }

    __shared__ float red[NM][NW];
    const int wave = tid >> 6;
    const int lane = tid & 63;
    if (lane == 0) {
        #pragma unroll
        for (int j = 0; j < NM; ++j) red[j][wave] = s[j];
    }
    __syncthreads();

    if (tid == 0) {
        double a[NM];
        #pragma unroll
        for (int j = 0; j < NM; ++j) {
            float acc = 0.0f;
            #pragma unroll
            for (int m = 0; m < NW; ++m) acc += red[j][m];
            a[j] = (double)acc;
        }
        const double S_w = a[0], S_wv = a[1], S_sewv = a[2];
        const double S_e = a[3], S_e2 = a[4], S_we = a[5], S_we2 = a[6];

        const double mse = S_sewv / S_wv;
        const double N   = (double)BN;
        const double num = 0.5 * (N * S_we2 + S_e2 * S_w - 2.0 * S_we * S_e);
        const double den = 0.5 * (N - 1.0) * S_w;
        const double c   = num / den;

        const bool   do_scale = (c > 1e-8) && (mse > 1e-8) && (c < mse);
        const double scale    = do_scale ? (mse / c) : 1.0;

        out[0] = (float)(0.5 * mse + 0.5 * (c * scale));
    }
}

extern "C" void kernel_launch(void* const* d_in, const int* in_sizes, int n_in,
                              void* d_out, int out_size, void* d_ws, size_t ws_size,
                              hipStream_t stream) {
    const float4* inp = (const float4*)d_in[0];
    const float4* tgt = (const float4*)d_in[1];
    float* out = (float*)d_out;
    loss_kernel<<<1, NT, 0, stream>>>(inp, tgt, out);
}